// Round 24
// baseline (24.079 us; speedup 1.0000x reference)
//
#include <hip/hip_runtime.h>

#define DEV __device__ __forceinline__

typedef unsigned u32;
typedef u32 u32x2 __attribute__((ext_vector_type(2)));
typedef _Float16 f16;
typedef f16   f16x8 __attribute__((ext_vector_type(8)));
typedef float f32x4 __attribute__((ext_vector_type(4)));

// ---------- DPP helpers ----------
template<int CTRL>
DEV int dpp_full(int src) {
    return __builtin_amdgcn_update_dpp(src, src, CTRL, 0xF, 0xF, false);
}
template<int CTRL, int RM, int BM>
DEV int dpp_masked(int old, int src) {
    return __builtin_amdgcn_update_dpp(old, src, CTRL, RM, BM, false);
}

// ---------- cross-lane xor-shuffle (r7-proven mix) ----------
template<int B>
DEV float lshfl(float x, bool px) {
    int xi = __float_as_int(x);
    if constexpr (B == 0) {
        return __int_as_float(dpp_full<0xB1>(xi));          // xor1
    } else if constexpr (B == 1) {
        return __int_as_float(dpp_full<0x4E>(xi));          // xor2
    } else if constexpr (B == 2) {
        return __int_as_float(__builtin_amdgcn_ds_swizzle(xi, 0x101F)); // xor4
    } else if constexpr (B == 3) {
        return __int_as_float(dpp_full<0x128>(xi));         // xor8
    } else if constexpr (B == 4) {
        return __int_as_float(__builtin_amdgcn_ds_swizzle(xi, 0x401F)); // xor16
    } else {
        u32x2 r = __builtin_amdgcn_permlane32_swap((u32)xi, (u32)xi, false, false);
        return __int_as_float((int)(px ? r.x : r.y));
    }
}

DEV bool probe32(int lane) {
    u32 p = (u32)((lane >> 5) & 1);
    u32x2 r = __builtin_amdgcn_permlane32_swap(p, p, false, false);
    return r.x == (p ^ 1u);
}

// ---------- complex pair primitives (fp32) ----------
DEV void rx_pair(float& r0, float& i0, float& r1, float& i1, float c, float s) {
    float nr0 = fmaf(c, r0,  s * i1);
    float ni0 = fmaf(c, i0, -s * r1);
    float nr1 = fmaf(c, r1,  s * i0);
    float ni1 = fmaf(c, i1, -s * r0);
    r0 = nr0; i0 = ni0; r1 = nr1; i1 = ni1;
}
DEV void ry_pair(float& r0, float& i0, float& r1, float& i1, float c, float s) {
    float nr0 = fmaf(c, r0, -s * r1);
    float ni0 = fmaf(c, i0, -s * i1);
    float nr1 = fmaf(c, r1,  s * r0);
    float ni1 = fmaf(c, i1,  s * i0);
    r0 = nr0; i0 = ni0; r1 = nr1; i1 = ni1;
}
DEV void rz_amp(float& r, float& i, float c, float ss) {
    float nr = fmaf(c, r, -ss * i);
    float ni = fmaf(c, i,  ss * r);
    r = nr; i = ni;
}

// ---------- gates on flat-index bit B (B = 7 - qubit), r7-verified ----------
template<int B>
DEV void apply_rx(float (&re)[4], float (&im)[4], int lane, bool px, float c, float s) {
    if constexpr (B == 7) {
        rx_pair(re[0], im[0], re[2], im[2], c, s);
        rx_pair(re[1], im[1], re[3], im[3], c, s);
    } else if constexpr (B == 6) {
        rx_pair(re[0], im[0], re[1], im[1], c, s);
        rx_pair(re[2], im[2], re[3], im[3], c, s);
    } else {
#pragma unroll
        for (int k = 0; k < 4; ++k) {
            float pr = lshfl<B>(re[k], px);
            float pi = lshfl<B>(im[k], px);
            re[k] = fmaf(c, re[k],  s * pi);
            im[k] = fmaf(c, im[k], -s * pr);
        }
    }
}
template<int B>
DEV void apply_ry(float (&re)[4], float (&im)[4], int lane, bool px, float c, float s) {
    if constexpr (B == 7) {
        ry_pair(re[0], im[0], re[2], im[2], c, s);
        ry_pair(re[1], im[1], re[3], im[3], c, s);
    } else if constexpr (B == 6) {
        ry_pair(re[0], im[0], re[1], im[1], c, s);
        ry_pair(re[2], im[2], re[3], im[3], c, s);
    } else {
        float ssel = ((lane >> B) & 1) ? s : -s;
#pragma unroll
        for (int k = 0; k < 4; ++k) {
            float pr = lshfl<B>(re[k], px);
            float pi = lshfl<B>(im[k], px);
            re[k] = fmaf(c, re[k], ssel * pr);
            im[k] = fmaf(c, im[k], ssel * pi);
        }
    }
}
template<int B>
DEV void apply_rz(float (&re)[4], float (&im)[4], int lane, float c, float s) {
    if constexpr (B == 7) {
        rz_amp(re[0], im[0], c, -s); rz_amp(re[1], im[1], c, -s);
        rz_amp(re[2], im[2], c,  s); rz_amp(re[3], im[3], c,  s);
    } else if constexpr (B == 6) {
        rz_amp(re[0], im[0], c, -s); rz_amp(re[1], im[1], c,  s);
        rz_amp(re[2], im[2], c, -s); rz_amp(re[3], im[3], c,  s);
    } else {
        float ss = ((lane >> B) & 1) ? s : -s;
#pragma unroll
        for (int k = 0; k < 4; ++k) rz_amp(re[k], im[k], c, ss);
    }
}
template<int BC, int BT>
DEV void apply_cnot(float (&re)[4], float (&im)[4], int lane, bool px) {
    if constexpr (BC == 7 && BT == 6) {
        float tr = re[2], ti = im[2];
        re[2] = re[3]; im[2] = im[3];
        re[3] = tr;    im[3] = ti;
    } else if constexpr (BC == 6) {
        re[1] = lshfl<5>(re[1], px); im[1] = lshfl<5>(im[1], px);
        re[3] = lshfl<5>(re[3], px); im[3] = lshfl<5>(im[3], px);
    } else if constexpr (BC == 5 && BT == 4) {
        bool ctrl = (lane >> 5) & 1;
#pragma unroll
        for (int k = 0; k < 4; ++k) {
            float pr = lshfl<4>(re[k], px);
            float pi = lshfl<4>(im[k], px);
            re[k] = ctrl ? pr : re[k];
            im[k] = ctrl ? pi : im[k];
        }
    } else if constexpr (BC == 4 && BT == 3) {
#pragma unroll
        for (int k = 0; k < 4; ++k) {
            int r = __float_as_int(re[k]), i = __float_as_int(im[k]);
            re[k] = __int_as_float(dpp_masked<0x128, 0xA, 0xF>(r, r));
            im[k] = __int_as_float(dpp_masked<0x128, 0xA, 0xF>(i, i));
        }
    } else if constexpr (BC == 3 && BT == 2) {
#pragma unroll
        for (int k = 0; k < 4; ++k) {
            int r = __float_as_int(re[k]), i = __float_as_int(im[k]);
            int tr = dpp_full<0x1B>(r), ti = dpp_full<0x1B>(i);
            re[k] = __int_as_float(dpp_masked<0x141, 0xF, 0xC>(r, tr));
            im[k] = __int_as_float(dpp_masked<0x141, 0xF, 0xC>(i, ti));
        }
    } else if constexpr (BC == 2 && BT == 1) {
#pragma unroll
        for (int k = 0; k < 4; ++k) {
            int r = __float_as_int(re[k]), i = __float_as_int(im[k]);
            re[k] = __int_as_float(dpp_masked<0x4E, 0xF, 0xA>(r, r));
            im[k] = __int_as_float(dpp_masked<0x4E, 0xF, 0xA>(i, i));
        }
    } else {
#pragma unroll
        for (int k = 0; k < 4; ++k) {
            re[k] = __int_as_float(dpp_full<0xB4>(__float_as_int(re[k])));
            im[k] = __int_as_float(dpp_full<0xB4>(__float_as_int(im[k])));
        }
    }
}

// ---------- kernel 1: build interleaved G/H (phase-folded U) ----------
// Unit layout (f16x8 units): u = ((kb*256+idx)*4 + kg)*2 + {0=g, 1=h}
// -> the (bg,bh) pair for one MFMA tile is 32 contiguous bytes (one line).

__global__ __launch_bounds__(512) void qa_genU(
    const float* __restrict__ params, f16* __restrict__ B)
{
    __shared__ float gs[96];
    __shared__ f16 Lg[8][256];
    __shared__ f16 Lh[8][256];

    int tid  = threadIdx.x;
    int w    = tid >> 6, lane = tid & 63;
    int j    = blockIdx.x * 8 + w;
    bool px  = probe32(lane);

    if (tid < 48) {
        float th = params[tid] * 0.5f;
        gs[2 * tid]     = __cosf(th);
        gs[2 * tid + 1] = __sinf(th);
    }
    __syncthreads();

    float re[4], im[4];
#pragma unroll
    for (int k = 0; k < 4; ++k) {
        re[k] = ((j >> 6) == k && (j & 63) == lane) ? 1.f : 0.f;
        im[k] = 0.f;
    }

#define VQ(l, i) { const int jj = (l) * 24 + (i) * 3;                       \
                   apply_ry<7 - (i)>(re, im, lane, px, gs[2*jj],   gs[2*jj+1]); \
                   apply_rz<7 - (i)>(re, im, lane,     gs[2*jj+2], gs[2*jj+3]); }
#define CN(i)    apply_cnot<7 - (i), 6 - (i)>(re, im, lane, px);
#define RXQ(l,i) { const int jj = (l) * 24 + (i) * 3 + 2;                   \
                   apply_rx<7 - (i)>(re, im, lane, px, gs[2*jj], gs[2*jj+1]); }
#define LAYER(l) \
    VQ(l,0) CN(0) VQ(l,1) CN(1) VQ(l,2) CN(2) VQ(l,3) CN(3) \
    VQ(l,4) CN(4) VQ(l,5) CN(5) VQ(l,6) CN(6) VQ(l,7)       \
    RXQ(l,0) RXQ(l,1) RXQ(l,2) RXQ(l,3) RXQ(l,4) RXQ(l,5) RXQ(l,6) RXQ(l,7)

    LAYER(0)
    LAYER(1)
#undef LAYER
#undef RXQ
#undef CN
#undef VQ

    // fold encoding phase (-i)^pc(j) into the column (sel wave-uniform)
    int sel = __popc((u32)j) & 3;
#pragma unroll
    for (int k = 0; k < 4; ++k) {
        int idx = k * 64 + lane;
        float g, h;
        if      (sel == 0) { g =  re[k]; h =  im[k]; }
        else if (sel == 1) { g =  im[k]; h = -re[k]; }
        else if (sel == 2) { g = -re[k]; h = -im[k]; }
        else               { g = -im[k]; h =  re[k]; }
        Lg[w][idx] = (f16)g;
        Lh[w][idx] = (f16)h;
    }
    __syncthreads();

    // coalesced writeout: thread t<256 -> g-unit for idx=t, t>=256 -> h-unit
    {
        int idx  = tid & 255;
        bool ish = tid >= 256;
        const f16* src = ish ? &Lh[0][0] : &Lg[0][0];
        f16x8 v;
#pragma unroll
        for (int wv = 0; wv < 8; ++wv) v[wv] = src[wv * 256 + idx];
        int kb = blockIdx.x >> 2, kgq = blockIdx.x & 3;
        int unit = ((kb * 256 + idx) * 4 + kgq) * 2 + (ish ? 1 : 0);
        *reinterpret_cast<f16x8*>(&B[unit * 8]) = v;
    }
}

// ---------- kernel 2: 32 rows/block, 16 waves, interleaved B loads ----------
// Wave w owns col-tile w: idx = w*16 + L, L = lane&15.
// Per kb-step: (bg,bh) = one 32B chunk (single cacheline), 2 A ds_reads,
// 4 MFMAs (B pair reused by 2 row-tiles).

__global__ __launch_bounds__(1024, 4) void qa_gemm(
    const float* __restrict__ x, const f16* __restrict__ B,
    float* __restrict__ out, int batch)
{
    __shared__ __align__(16) f16 Ap[32 * 256];
    __shared__ float zb[16][32][8];

    int tid  = threadIdx.x;
    int w    = tid >> 6, lane = tid & 63;
    int b0   = blockIdx.x * 32;
    if (b0 >= batch) return;

    // ---- encode rows w*2, w*2+1: P = magnitude product (no phase) ----
#pragma unroll
    for (int e = 0; e < 2; ++e) {
        int rl = w * 2 + e;
        int bb = b0 + rl; if (bb >= batch) bb = batch - 1;
        const float* xb = x + bb * 8;
        float4 xlo = *(const float4*)xb;
        float4 xhi = *(const float4*)(xb + 4);
        float c_[8], s_[8];
        __sincosf(xlo.x * 0.5f, &s_[0], &c_[0]);
        __sincosf(xlo.y * 0.5f, &s_[1], &c_[1]);
        __sincosf(xlo.z * 0.5f, &s_[2], &c_[2]);
        __sincosf(xlo.w * 0.5f, &s_[3], &c_[3]);
        __sincosf(xhi.x * 0.5f, &s_[4], &c_[4]);
        __sincosf(xhi.y * 0.5f, &s_[5], &c_[5]);
        __sincosf(xhi.z * 0.5f, &s_[6], &c_[6]);
        __sincosf(xhi.w * 0.5f, &s_[7], &c_[7]);

        float m6;
        m6  = ((lane >> 5) & 1) ? s_[2] : c_[2];
        m6 *= ((lane >> 4) & 1) ? s_[3] : c_[3];
        m6 *= ((lane >> 3) & 1) ? s_[4] : c_[4];
        m6 *= ((lane >> 2) & 1) ? s_[5] : c_[5];
        m6 *= ((lane >> 1) & 1) ? s_[6] : c_[6];
        m6 *= ( lane       & 1) ? s_[7] : c_[7];
        float kf[4] = { c_[0] * c_[1], c_[0] * s_[1], s_[0] * c_[1], s_[0] * s_[1] };
        int sw = (rl & 7) << 3;
#pragma unroll
        for (int k = 0; k < 4; ++k) {
            int j  = k * 64 + lane;
            int hi = rl * 256 + (j ^ sw);
            Ap[hi] = (f16)(m6 * kf[k]);
        }
    }
    __syncthreads();

    // ---- K loop: 8 steps of 32; one 32B (bg,bh) chunk reused by 2 row-tiles ----
    f32x4 accR[2], accI[2];
#pragma unroll
    for (int rt = 0; rt < 2; ++rt) { accR[rt] = (f32x4)0.f; accI[rt] = (f32x4)0.f; }

    int L       = lane & 15;
    int colbase = w * 16 + L;
    int kg      = lane >> 4;
    const f16x8* B16 = reinterpret_cast<const f16x8*>(B);

#pragma unroll
    for (int kb = 0; kb < 8; ++kb) {
        int bo  = ((kb * 256 + colbase) * 4 + kg) * 2;
        f16x8 bg = B16[bo];
        f16x8 bh = B16[bo + 1];
#pragma unroll
        for (int rt = 0; rt < 2; ++rt) {
            int arow = rt * 16 + L;
            int afi  = arow * 32 + ((kb * 4 + kg) ^ (arow & 7));
            f16x8 ap = *reinterpret_cast<const f16x8*>(&Ap[afi * 8]);
            accR[rt] = __builtin_amdgcn_mfma_f32_16x16x32_f16(ap, bg, accR[rt], 0, 0, 0);
            accI[rt] = __builtin_amdgcn_mfma_f32_16x16x32_f16(ap, bh, accI[rt], 0, 0, 0);
        }
    }

    // ---- separable Walsh epilogue ----
    // D layout: batch row = rt*16 + (lane>>4)*4 + r, idx-low4 = L (m89-verified).
    bool wr = (L < 8);
#pragma unroll
    for (int rt = 0; rt < 2; ++rt) {
#pragma unroll
        for (int r = 0; r < 4; ++r) {
            float S = fmaf(accR[rt][r], accR[rt][r], accI[rt][r] * accI[rt][r]);

            // pruned WH over lane bits 0..3
            float P;
            P = lshfl<0>(S, false); float w0d = S - P; S += P;
            P = lshfl<1>(S, false); float w1d = S - P; S += P;
            P = lshfl<2>(S, false); float w2d = S - P; S += P;
            P = lshfl<3>(S, false); float w3d = S - P; S += P;   // S = full sum
            w0d += lshfl<1>(w0d, false); w0d += lshfl<2>(w0d, false); w0d += lshfl<3>(w0d, false);
            w1d += lshfl<2>(w1d, false); w1d += lshfl<3>(w1d, false);
            w2d += lshfl<3>(w2d, false);

            if (wr) {
                // writer lane L writes q = L; q0..3 signs from w bits 3..0
                float val = (L == 0) ? ((w & 8) ? -S : S)
                          : (L == 1) ? ((w & 4) ? -S : S)
                          : (L == 2) ? ((w & 2) ? -S : S)
                          : (L == 3) ? ((w & 1) ? -S : S)
                          : (L == 4) ? w3d          // lane 4: bit3=0 -> +
                          : (L == 5) ? -w2d         // lane 5: bit2=1 -> -
                          : (L == 6) ? -w1d         // lane 6: bit1=1 -> -
                          :            -w0d;        // lane 7: bit0=1 -> -
                zb[w][rt * 16 + (lane >> 4) * 4 + r][L] = val;
            }
        }
    }
    __syncthreads();

    // ---- final: sum 16 col-groups, write 32 rows x 8 q ----
    if (tid < 256) {
        int row = tid >> 3, q = tid & 7;
        float v = 0.f;
#pragma unroll
        for (int g = 0; g < 16; ++g) v += zb[g][row][q];
        if (b0 + row < batch) out[(b0 + row) * 8 + q] = v;
    }
}

extern "C" void kernel_launch(void* const* d_in, const int* in_sizes, int n_in,
                              void* d_out, int out_size, void* d_ws, size_t ws_size,
                              hipStream_t stream) {
    const float* x      = (const float*)d_in[0];   // (BATCH, 8)
    const float* params = (const float*)d_in[1];   // (2, 8, 3) = 48
    float* out = (float*)d_out;

    f16* B = (f16*)d_ws;                // 256 KB interleaved G/H

    int batch = in_sizes[0] / 8;

    qa_genU<<<32, 512, 0, stream>>>(params, B);

    int blocks = (batch + 31) / 32;
    qa_gemm<<<blocks, 1024, 0, stream>>>(x, B, out, batch);
}